// Round 1
// baseline (361.114 us; speedup 1.0000x reference)
//
#include <hip/hip_runtime.h>

#define DIM 64
#define NW 8188          // number of output windows
#define OUT_STRIDE 4160  // 64 + 64*64 floats per output row
#define WPG 16           // windows per group
#define NG 512           // ceil(NW / WPG): 511 full groups + 1 group of 12
#define TI 64            // increments staged per LDS tile in k_totals

// ---------------------------------------------------------------------------
// K1: base = sum_{t=1..127} m_t (x) dz_t  (signature level 2 of x[:128])
// ---------------------------------------------------------------------------
__global__ __launch_bounds__(256) void k_base(const float* __restrict__ x,
                                              float* __restrict__ B) {
  __shared__ float sx[128][DIM];  // 32 KB
  int tid = threadIdx.x;
  for (int e = tid; e < 128 * DIM; e += 256) sx[e >> 6][e & 63] = x[e];
  __syncthreads();
  int a0 = (tid >> 4) << 2, b0 = (tid & 15) << 2;
  float acc[4][4] = {};
  for (int t = 1; t < 128; ++t) {
    float m[4], d[4];
#pragma unroll
    for (int i = 0; i < 4; ++i)
      m[i] = 0.5f * (sx[t][a0 + i] + sx[t - 1][a0 + i]) - sx[0][a0 + i];
#pragma unroll
    for (int j = 0; j < 4; ++j) d[j] = sx[t][b0 + j] - sx[t - 1][b0 + j];
#pragma unroll
    for (int i = 0; i < 4; ++i)
#pragma unroll
      for (int j = 0; j < 4; ++j) acc[i][j] += m[i] * d[j];
  }
#pragma unroll
  for (int i = 0; i < 4; ++i)
#pragma unroll
    for (int j = 0; j < 4; ++j) B[(a0 + i) * DIM + b0 + j] = acc[i][j];
}

// ---------------------------------------------------------------------------
// K2: per-group totals T[g] = sum over the group's 32*WPG increments
// group g covers increments t in [128 + 512g, 128 + 512g + 32*wcount)
// ---------------------------------------------------------------------------
__global__ __launch_bounds__(256) void k_totals(const float* __restrict__ x,
                                                float* __restrict__ T) {
  int g = blockIdx.x, tid = threadIdx.x;
  int wcount = min(WPG, NW - g * WPG);
  int t0 = 128 + 512 * g;
  int nInc = 32 * wcount;  // 512 or 384, both multiples of TI=64
  __shared__ float sm[TI][DIM];  // 16 KB
  __shared__ float sd[TI][DIM];  // 16 KB
  int a0 = (tid >> 4) << 2, b0 = (tid & 15) << 2;
  float acc[4][4] = {};
  for (int tt = 0; tt < nInc; tt += TI) {
    // stage m and dz rows for TI increments (coalesced: consecutive tid -> a)
    for (int e = tid; e < TI * DIM; e += 256) {
      int ti = e >> 6, a = e & 63;
      int t = t0 + tt + ti;
      float xc = x[t * DIM + a], xp = x[(t - 1) * DIM + a];
      sm[ti][a] = 0.5f * (xc + xp) - x[a];
      sd[ti][a] = xc - xp;
    }
    __syncthreads();
#pragma unroll 4
    for (int ti = 0; ti < TI; ++ti) {
      const float4 mv = *(const float4*)(&sm[ti][a0]);
      const float4 dv = *(const float4*)(&sd[ti][b0]);
      acc[0][0] += mv.x * dv.x; acc[0][1] += mv.x * dv.y; acc[0][2] += mv.x * dv.z; acc[0][3] += mv.x * dv.w;
      acc[1][0] += mv.y * dv.x; acc[1][1] += mv.y * dv.y; acc[1][2] += mv.y * dv.z; acc[1][3] += mv.y * dv.w;
      acc[2][0] += mv.z * dv.x; acc[2][1] += mv.z * dv.y; acc[2][2] += mv.z * dv.z; acc[2][3] += mv.z * dv.w;
      acc[3][0] += mv.w * dv.x; acc[3][1] += mv.w * dv.y; acc[3][2] += mv.w * dv.z; acc[3][3] += mv.w * dv.w;
    }
    __syncthreads();
  }
  float* Tg = T + (size_t)g * 4096;
#pragma unroll
  for (int i = 0; i < 4; ++i)
    *(float4*)(&Tg[(a0 + i) * DIM + b0]) =
        make_float4(acc[i][0], acc[i][1], acc[i][2], acc[i][3]);
}

// ---------------------------------------------------------------------------
// K3: exclusive scan over group totals: O[g] = B + sum_{h<g} T[h]
// 4096 threads, one (a,b) entry each, serial over NG groups
// ---------------------------------------------------------------------------
__global__ __launch_bounds__(256) void k_scan(const float* __restrict__ B,
                                              const float* __restrict__ T,
                                              float* __restrict__ O) {
  int e = blockIdx.x * 256 + threadIdx.x;
  float acc = B[e];
#pragma unroll 4
  for (int g = 0; g < NG; ++g) {
    O[(size_t)g * 4096 + e] = acc;
    acc += T[(size_t)g * 4096 + e];
  }
}

// ---------------------------------------------------------------------------
// K4: per group, running prefix across its windows; emit each output row
// ---------------------------------------------------------------------------
__global__ __launch_bounds__(256) void k_emit(const float* __restrict__ x,
                                              const float* __restrict__ O,
                                              float* __restrict__ out) {
  int g = blockIdx.x, tid = threadIdx.x;
  int wcount = min(WPG, NW - g * WPG);
  int t0 = 128 + 512 * g;
  int a0 = (tid >> 4) << 2, b0 = (tid & 15) << 2;
  __shared__ float sm[32][DIM];  // 8 KB
  __shared__ float sd[32][DIM];  // 8 KB
  float acc[4][4];
  const float* Og = O + (size_t)g * 4096;
#pragma unroll
  for (int i = 0; i < 4; ++i) {
    const float4 v = *(const float4*)(&Og[(a0 + i) * DIM + b0]);
    acc[i][0] = v.x; acc[i][1] = v.y; acc[i][2] = v.z; acc[i][3] = v.w;
  }
  for (int w = 0; w < wcount; ++w) {
    int tw = t0 + 32 * w;  // first increment of this window
    for (int e = tid; e < 32 * DIM; e += 256) {
      int ti = e >> 6, a = e & 63;
      int t = tw + ti;
      float xc = x[t * DIM + a], xp = x[(t - 1) * DIM + a];
      sm[ti][a] = 0.5f * (xc + xp) - x[a];
      sd[ti][a] = xc - xp;
    }
    __syncthreads();
#pragma unroll 4
    for (int ti = 0; ti < 32; ++ti) {
      const float4 mv = *(const float4*)(&sm[ti][a0]);
      const float4 dv = *(const float4*)(&sd[ti][b0]);
      acc[0][0] += mv.x * dv.x; acc[0][1] += mv.x * dv.y; acc[0][2] += mv.x * dv.z; acc[0][3] += mv.x * dv.w;
      acc[1][0] += mv.y * dv.x; acc[1][1] += mv.y * dv.y; acc[1][2] += mv.y * dv.z; acc[1][3] += mv.y * dv.w;
      acc[2][0] += mv.z * dv.x; acc[2][1] += mv.z * dv.y; acc[2][2] += mv.z * dv.z; acc[2][3] += mv.z * dv.w;
      acc[3][0] += mv.w * dv.x; acc[3][1] += mv.w * dv.y; acc[3][2] += mv.w * dv.z; acc[3][3] += mv.w * dv.w;
    }
    // emit output row j: level 1 (exact telescoped) then level 2
    int j = g * WPG + w;
    float* row = out + (size_t)j * OUT_STRIDE;
    if (tid < 64) row[tid] = x[(tw + 31) * DIM + tid] - x[tid];
#pragma unroll
    for (int i = 0; i < 4; ++i)
      *(float4*)(&row[64 + (a0 + i) * DIM + b0]) =
          make_float4(acc[i][0], acc[i][1], acc[i][2], acc[i][3]);
    __syncthreads();  // protect sm/sd before next window's staging
  }
}

extern "C" void kernel_launch(void* const* d_in, const int* in_sizes, int n_in,
                              void* d_out, int out_size, void* d_ws, size_t ws_size,
                              hipStream_t stream) {
  const float* x = (const float*)d_in[0];
  float* out = (float*)d_out;
  float* B = (float*)d_ws;                 // 4096 floats
  float* T = B + 4096;                     // NG * 4096 floats
  float* O = T + (size_t)NG * 4096;        // NG * 4096 floats
  k_base<<<1, 256, 0, stream>>>(x, B);
  k_totals<<<NG, 256, 0, stream>>>(x, T);
  k_scan<<<16, 256, 0, stream>>>(B, T, O);
  k_emit<<<NG, 256, 0, stream>>>(x, O, out);
}

// Round 2
// 245.211 us; speedup vs baseline: 1.4727x; 1.4727x over previous
//
#include <hip/hip_runtime.h>

#define DIM 64
#define NW 8188          // number of output windows
#define OUT_STRIDE 4160  // 64 + 64*64 floats per output row
#define WPG 8            // windows per group
#define NG 1024          // ceil(NW / WPG): 1023 full + 1 group of 4
#define NCHUNK 32        // groups per scan chunk
#define NC 32            // number of chunks (NC*NCHUNK == NG)

// ---------------------------------------------------------------------------
// K1: B = sum_{t=1..127} m_t (x) dz_t   (level-2 signature of x[:128])
// ---------------------------------------------------------------------------
__global__ __launch_bounds__(256) void k_base(const float* __restrict__ x,
                                              float* __restrict__ B) {
  __shared__ float sx[128][DIM];  // 32 KB
  const int tid = threadIdx.x;
  for (int f = tid; f < 128 * (DIM / 4); f += 256) {
    const int r = f >> 4, c4 = (f & 15) << 2;
    *(float4*)&sx[r][c4] = *(const float4*)&x[(size_t)r * DIM + c4];
  }
  __syncthreads();
  const int a0 = (tid >> 4) << 2, b0 = (tid & 15) << 2;
  float acc[4][4] = {};
  for (int t = 1; t < 128; ++t) {
    float m[4], d[4];
#pragma unroll
    for (int i = 0; i < 4; ++i)
      m[i] = 0.5f * (sx[t][a0 + i] + sx[t - 1][a0 + i]) - sx[0][a0 + i];
#pragma unroll
    for (int j = 0; j < 4; ++j) d[j] = sx[t][b0 + j] - sx[t - 1][b0 + j];
#pragma unroll
    for (int i = 0; i < 4; ++i)
#pragma unroll
      for (int j = 0; j < 4; ++j) acc[i][j] += m[i] * d[j];
  }
#pragma unroll
  for (int i = 0; i < 4; ++i)
    *(float4*)&B[(a0 + i) * DIM + b0] =
        make_float4(acc[i][0], acc[i][1], acc[i][2], acc[i][3]);
}

// ---------------------------------------------------------------------------
// K2 (EMIT=0): per-group totals T[g] over 32*WPG increments
// K5 (EMIT=1): resume from scanned offset (T[g]=intra-chunk prefix, C=chunk
//              offsets incl. base), accumulate each window, emit output rows
// ---------------------------------------------------------------------------
template <bool EMIT>
__global__ __launch_bounds__(256, 4) void k_sweep(const float* __restrict__ x,
                                                  float* __restrict__ T,
                                                  const float* __restrict__ C,
                                                  float* __restrict__ out) {
  __shared__ float sm[2][32][DIM];  // 16 KB
  __shared__ float sd[2][32][DIM];  // 16 KB
  const int g = blockIdx.x, tid = threadIdx.x;
  const int wcount = min(WPG, NW - g * WPG);
  const int t0 = 128 + 32 * WPG * g;
  const int a0 = (tid >> 4) << 2, b0 = (tid & 15) << 2;
  const int a4 = b0;  // staging column quad, same formula as b0
  const float4 x0v = *(const float4*)&x[a4];

  float acc[4][4];
  if (EMIT) {
    const float* Tg = T + (size_t)g * 4096;
    const float* Cc = C + (size_t)(g / NCHUNK) * 4096;
#pragma unroll
    for (int i = 0; i < 4; ++i) {
      const float4 tv = *(const float4*)&Tg[(a0 + i) * DIM + b0];
      const float4 cv = *(const float4*)&Cc[(a0 + i) * DIM + b0];
      acc[i][0] = tv.x + cv.x;
      acc[i][1] = tv.y + cv.y;
      acc[i][2] = tv.z + cv.z;
      acc[i][3] = tv.w + cv.w;
    }
  } else {
#pragma unroll
    for (int i = 0; i < 4; ++i)
      acc[i][0] = acc[i][1] = acc[i][2] = acc[i][3] = 0.f;
  }

  // stage one 32-increment window (rows tw..tw+31) into buffer bb, float4s
  auto stage = [&](int bb, int tw) {
#pragma unroll
    for (int k = 0; k < 2; ++k) {
      const int ti = (tid >> 4) + (k << 4);
      const size_t t = (size_t)tw + ti;
      const float4 xc = *(const float4*)&x[t * DIM + a4];
      const float4 xp = *(const float4*)&x[(t - 1) * DIM + a4];
      float4 m, d;
      m.x = 0.5f * (xc.x + xp.x) - x0v.x;
      m.y = 0.5f * (xc.y + xp.y) - x0v.y;
      m.z = 0.5f * (xc.z + xp.z) - x0v.z;
      m.w = 0.5f * (xc.w + xp.w) - x0v.w;
      d.x = xc.x - xp.x;
      d.y = xc.y - xp.y;
      d.z = xc.z - xp.z;
      d.w = xc.w - xp.w;
      *(float4*)&sm[bb][ti][a4] = m;
      *(float4*)&sd[bb][ti][a4] = d;
    }
  };

  stage(0, t0);
  for (int w = 0; w < wcount; ++w) {
    const int bb = w & 1;
    if (w + 1 < wcount) stage(bb ^ 1, t0 + 32 * (w + 1));
    __syncthreads();  // buf bb staged (prev iter / prologue); all waves synced
#pragma unroll 8
    for (int ti = 0; ti < 32; ++ti) {
      const float4 mv = *(const float4*)&sm[bb][ti][a0];
      const float4 dv = *(const float4*)&sd[bb][ti][b0];
      acc[0][0] += mv.x * dv.x; acc[0][1] += mv.x * dv.y; acc[0][2] += mv.x * dv.z; acc[0][3] += mv.x * dv.w;
      acc[1][0] += mv.y * dv.x; acc[1][1] += mv.y * dv.y; acc[1][2] += mv.y * dv.z; acc[1][3] += mv.y * dv.w;
      acc[2][0] += mv.z * dv.x; acc[2][1] += mv.z * dv.y; acc[2][2] += mv.z * dv.z; acc[2][3] += mv.z * dv.w;
      acc[3][0] += mv.w * dv.x; acc[3][1] += mv.w * dv.y; acc[3][2] += mv.w * dv.z; acc[3][3] += mv.w * dv.w;
    }
    if (EMIT) {
      const int j = g * WPG + w;
      float* row = out + (size_t)j * OUT_STRIDE;
      const int n = t0 + 32 * w + 31;  // window end index
      if (tid < 64) row[tid] = x[(size_t)n * DIM + tid] - x[tid];
#pragma unroll
      for (int i = 0; i < 4; ++i)
        *(float4*)&row[64 + (a0 + i) * DIM + b0] =
            make_float4(acc[i][0], acc[i][1], acc[i][2], acc[i][3]);
    }
    __syncthreads();  // all waves done reading bb before it is re-staged
  }
  if (!EMIT) {
    float* Tg = T + (size_t)g * 4096;
#pragma unroll
    for (int i = 0; i < 4; ++i)
      *(float4*)&Tg[(a0 + i) * DIM + b0] =
          make_float4(acc[i][0], acc[i][1], acc[i][2], acc[i][3]);
  }
}

// ---------------------------------------------------------------------------
// K3: intra-chunk exclusive scan, in place. T[g] <- sum_{h in chunk, h<g} T[h]
//     C[c] <- chunk total.   grid = NC*16 blocks (one chunk per 16 blocks)
// ---------------------------------------------------------------------------
__global__ __launch_bounds__(256) void k_scanA(float* __restrict__ T,
                                               float* __restrict__ C) {
  const int e = (blockIdx.x & 15) * 256 + threadIdx.x;  // element 0..4095
  const int c = blockIdx.x >> 4;                        // chunk 0..NC-1
  float acc = 0.f;
  const size_t base = (size_t)c * NCHUNK * 4096 + e;
#pragma unroll 8
  for (int g = 0; g < NCHUNK; ++g) {
    const size_t idx = base + (size_t)g * 4096;
    const float t = T[idx];
    T[idx] = acc;
    acc += t;
  }
  C[(size_t)c * 4096 + e] = acc;
}

// ---------------------------------------------------------------------------
// K4: scan chunk totals in place, seeding with base B.
//     C[c] <- B + sum_{c'<c} C[c']
// ---------------------------------------------------------------------------
__global__ __launch_bounds__(256) void k_scanB(const float* __restrict__ B,
                                               float* __restrict__ C) {
  const int e = blockIdx.x * 256 + threadIdx.x;  // grid 16 -> e < 4096
  float acc = B[e];
#pragma unroll 8
  for (int c = 0; c < NC; ++c) {
    const size_t idx = (size_t)c * 4096 + e;
    const float t = C[idx];
    C[idx] = acc;
    acc += t;
  }
}

extern "C" void kernel_launch(void* const* d_in, const int* in_sizes, int n_in,
                              void* d_out, int out_size, void* d_ws, size_t ws_size,
                              hipStream_t stream) {
  const float* x = (const float*)d_in[0];
  float* out = (float*)d_out;
  float* B = (float*)d_ws;             // 4096 floats
  float* T = B + 4096;                 // NG * 4096 floats
  float* C = T + (size_t)NG * 4096;    // NC * 4096 floats
  k_base<<<1, 256, 0, stream>>>(x, B);
  k_sweep<false><<<NG, 256, 0, stream>>>(x, T, C, out);
  k_scanA<<<NC * 16, 256, 0, stream>>>(T, C);
  k_scanB<<<16, 256, 0, stream>>>(B, C);
  k_sweep<true><<<NG, 256, 0, stream>>>(x, T, C, out);
}

// Round 3
// 243.929 us; speedup vs baseline: 1.4804x; 1.0053x over previous
//
#include <hip/hip_runtime.h>

#define DIM 64
#define NW 8188          // number of output windows
#define OUT_STRIDE 4160  // 64 + 64*64 floats per output row
#define NCHUNK 32        // groups per scan chunk

// ---------------------------------------------------------------------------
// Sweep kernel. EMIT=0: write per-group totals T[g] (sum of m (x) dz over the
// group's 32*WPG increments). EMIT=1: T[g] holds the intra-chunk exclusive
// prefix and C[g/NCHUNK] the chunk offset (incl. prefix-base signature);
// resume, accumulate window by window, emit output rows.
// T14 structure: loads for window w+1 are issued into registers right after
// the compute-entry barrier (in flight during the FMA loop); the reg->LDS
// transform+write happens at the top of the next iteration.
// ---------------------------------------------------------------------------
template <int WPGv, bool EMIT>
__global__ __launch_bounds__(256) void k_sweep(const float* __restrict__ x,
                                               float* __restrict__ T,
                                               const float* __restrict__ C,
                                               float* __restrict__ out) {
  __shared__ float sm[32][DIM];  // 8 KB
  __shared__ float sd[32][DIM];  // 8 KB
  const int g = blockIdx.x, tid = threadIdx.x;
  const int wcount = min(WPGv, NW - g * WPGv);
  const int t0 = 128 + 32 * WPGv * g;
  const int a0 = (tid >> 4) << 2, b0 = (tid & 15) << 2;
  const int a4 = b0;                       // staging column quad
  const int ti0 = tid >> 4, ti1 = ti0 + 16;  // staging rows
  const float4 x0v = *(const float4*)&x[a4];

  float acc[4][4];
  if (EMIT) {
    const float* Tg = T + (size_t)g * 4096;
    const float* Cc = C + (size_t)(g / NCHUNK) * 4096;
#pragma unroll
    for (int i = 0; i < 4; ++i) {
      const float4 tv = *(const float4*)&Tg[(a0 + i) * DIM + b0];
      const float4 cv = *(const float4*)&Cc[(a0 + i) * DIM + b0];
      acc[i][0] = tv.x + cv.x; acc[i][1] = tv.y + cv.y;
      acc[i][2] = tv.z + cv.z; acc[i][3] = tv.w + cv.w;
    }
  } else {
#pragma unroll
    for (int i = 0; i < 4; ++i)
      acc[i][0] = acc[i][1] = acc[i][2] = acc[i][3] = 0.f;
  }

  // raw next-window rows held in registers (the "second buffer")
  float4 c0, p0, c1, p1;
  auto issue = [&](int tw) {
    c0 = *(const float4*)&x[(size_t)(tw + ti0) * DIM + a4];
    p0 = *(const float4*)&x[(size_t)(tw + ti0 - 1) * DIM + a4];
    c1 = *(const float4*)&x[(size_t)(tw + ti1) * DIM + a4];
    p1 = *(const float4*)&x[(size_t)(tw + ti1 - 1) * DIM + a4];
  };
  issue(t0);

  for (int w = 0; w < wcount; ++w) {
    // transform regs -> m,d (vmcnt wait lands here; loads had a full compute
    // phase to complete for w>0)
    float4 m0, d0, m1, d1;
    m0.x = 0.5f * (c0.x + p0.x) - x0v.x; m0.y = 0.5f * (c0.y + p0.y) - x0v.y;
    m0.z = 0.5f * (c0.z + p0.z) - x0v.z; m0.w = 0.5f * (c0.w + p0.w) - x0v.w;
    d0.x = c0.x - p0.x; d0.y = c0.y - p0.y; d0.z = c0.z - p0.z; d0.w = c0.w - p0.w;
    m1.x = 0.5f * (c1.x + p1.x) - x0v.x; m1.y = 0.5f * (c1.y + p1.y) - x0v.y;
    m1.z = 0.5f * (c1.z + p1.z) - x0v.z; m1.w = 0.5f * (c1.w + p1.w) - x0v.w;
    d1.x = c1.x - p1.x; d1.y = c1.y - p1.y; d1.z = c1.z - p1.z; d1.w = c1.w - p1.w;
    if (w) __syncthreads();  // readers of the previous window are done
    *(float4*)&sm[ti0][a4] = m0; *(float4*)&sd[ti0][a4] = d0;
    *(float4*)&sm[ti1][a4] = m1; *(float4*)&sd[ti1][a4] = d1;
    __syncthreads();         // window w staged for everyone
    if (w + 1 < wcount) issue(t0 + 32 * (w + 1));  // in flight during compute
#pragma unroll 8
    for (int ti = 0; ti < 32; ++ti) {
      const float4 mv = *(const float4*)&sm[ti][a0];
      const float4 dv = *(const float4*)&sd[ti][b0];
      acc[0][0] += mv.x * dv.x; acc[0][1] += mv.x * dv.y; acc[0][2] += mv.x * dv.z; acc[0][3] += mv.x * dv.w;
      acc[1][0] += mv.y * dv.x; acc[1][1] += mv.y * dv.y; acc[1][2] += mv.y * dv.z; acc[1][3] += mv.y * dv.w;
      acc[2][0] += mv.z * dv.x; acc[2][1] += mv.z * dv.y; acc[2][2] += mv.z * dv.z; acc[2][3] += mv.z * dv.w;
      acc[3][0] += mv.w * dv.x; acc[3][1] += mv.w * dv.y; acc[3][2] += mv.w * dv.z; acc[3][3] += mv.w * dv.w;
    }
    if (EMIT) {
      const int j = g * WPGv + w;
      float* row = out + (size_t)j * OUT_STRIDE;
      const int n = t0 + 32 * w + 31;  // window-end path index
      if (tid < 64) row[tid] = x[(size_t)n * DIM + tid] - x[tid];
#pragma unroll
      for (int i = 0; i < 4; ++i)
        *(float4*)&row[64 + (a0 + i) * DIM + b0] =
            make_float4(acc[i][0], acc[i][1], acc[i][2], acc[i][3]);
    }
  }
  if (!EMIT) {
    float* Tg = T + (size_t)g * 4096;
#pragma unroll
    for (int i = 0; i < 4; ++i)
      *(float4*)&Tg[(a0 + i) * DIM + b0] =
          make_float4(acc[i][0], acc[i][1], acc[i][2], acc[i][3]);
  }
}

// ---------------------------------------------------------------------------
// Intra-chunk exclusive scan of group totals, in place; C[c] = chunk total.
// grid = NC*16 blocks (16 blocks cover the 4096 elements of one chunk).
// ---------------------------------------------------------------------------
template <int NGv>
__global__ __launch_bounds__(256) void k_scanA(float* __restrict__ T,
                                               float* __restrict__ C) {
  const int c = blockIdx.x >> 4;
  const int e = (blockIdx.x & 15) * 256 + threadIdx.x;
  const int gbeg = c * NCHUNK, gend = min(gbeg + NCHUNK, NGv);
  float acc = 0.f;
  for (int g = gbeg; g < gend; ++g) {
    const size_t idx = (size_t)g * 4096 + e;
    const float t = T[idx];
    T[idx] = acc;
    acc += t;
  }
  C[(size_t)c * 4096 + e] = acc;
}

// ---------------------------------------------------------------------------
// Chunk-total exclusive scan, in place, seeded with the level-2 signature of
// x[:128] (the prefix base), computed here from LDS-staged x (fuses old
// k_base). 16 blocks x 256 threads = 4096 elements.
// ---------------------------------------------------------------------------
template <int NCv>
__global__ __launch_bounds__(256) void k_scanB(const float* __restrict__ x,
                                               float* __restrict__ C) {
  __shared__ float sx[128][DIM];  // 32 KB
  const int tid = threadIdx.x;
  for (int f = tid; f < 128 * (DIM / 4); f += 256) {
    const int r = f >> 4, c4 = (f & 15) << 2;
    *(float4*)&sx[r][c4] = *(const float4*)&x[(size_t)r * DIM + c4];
  }
  __syncthreads();
  const int e = blockIdx.x * 256 + tid;
  const int a = e >> 6, b = e & 63;  // a uniform per wave, b = lane
  float acc = 0.f;
  for (int t = 1; t < 128; ++t)
    acc += (0.5f * (sx[t][a] + sx[t - 1][a]) - sx[0][a]) *
           (sx[t][b] - sx[t - 1][b]);
  for (int c = 0; c < NCv; ++c) {
    const size_t idx = (size_t)c * 4096 + e;
    const float t = C[idx];
    C[idx] = acc;
    acc += t;
  }
}

extern "C" void kernel_launch(void* const* d_in, const int* in_sizes, int n_in,
                              void* d_out, int out_size, void* d_ws, size_t ws_size,
                              hipStream_t stream) {
  const float* x = (const float*)d_in[0];
  float* out = (float*)d_out;
  // Primary: WPG=4 -> NG=2047 (NW = 4*2047 exactly), NC=ceil(2047/32)=64.
  // Fallback (small ws): WPG=8 -> NG=1024, NC=32.
  const size_t need4 = (size_t)(2047 + 64) * 4096 * sizeof(float);
  if (ws_size >= need4) {
    float* T = (float*)d_ws;
    float* C = T + (size_t)2047 * 4096;
    k_sweep<4, false><<<2047, 256, 0, stream>>>(x, T, nullptr, nullptr);
    k_scanA<2047><<<64 * 16, 256, 0, stream>>>(T, C);
    k_scanB<64><<<16, 256, 0, stream>>>(x, C);
    k_sweep<4, true><<<2047, 256, 0, stream>>>(x, T, C, out);
  } else {
    float* T = (float*)d_ws;
    float* C = T + (size_t)1024 * 4096;
    k_sweep<8, false><<<1024, 256, 0, stream>>>(x, T, nullptr, nullptr);
    k_scanA<1024><<<32 * 16, 256, 0, stream>>>(T, C);
    k_scanB<32><<<16, 256, 0, stream>>>(x, C);
    k_sweep<8, true><<<1024, 256, 0, stream>>>(x, T, C, out);
  }
}